// Round 15
// baseline (256.169 us; speedup 1.0000x reference)
//
#include <hip/hip_runtime.h>

// Born-series scattering, fully fused recompute-G approach.
// M=4096 pts, 4 wavenumbers (0.5,1,1.5,2), 5 Born iterations, 64 obs dirs.
// R4: bit-faithful D^2 (Gram rounding sequence) -> absmax 0.0.
// R5-R8: atomics eliminated; fused chunk-reduce.
// R9-R14: matvec plateau ~25us. Duty x residency model: per-wave duty is
//   chain-limited ~11% (compiler won't cross-interleave bodies: R12/R13);
//   1024 blocks = 4 waves/SIMD -> ~45% busy. Never tested: 2048 blocks WITH
//   the 2-row body and partial stores (R6's 2048-block run was confounded by
//   atomic serialization).
// R15: C=256 chunks (TC=16) x 8 rgs x 2 rows/thread = 2048 blocks =
//   8 blocks/CU = 8 waves/SIMD. Partials 33.6MB; reduce deepens to 256.
//
// ws layout (floats):
//   colpack[M][12]: x,y,z,r2, ar[4], ai[4]          (a = C * vw * psi, per k)
//   cvw[M]; p0r[4][M], p0i[4][M]; yr[4][M], yi[4][M] (fallback)
//   part[C][4][M] of float2                          (partials, 33.6MB)

#define MM 4096
#define NK 4
#define CGREEN 0.07957747154594767f   // 1/(4*pi)
#define INV2PI 0.15915494309189535f   // 1/(2*pi)

#define OFF_VW   49152
#define OFF_P0R  53248
#define OFF_P0I  69632
#define OFF_YR   86016
#define OFF_YI   102400
#define OFF_PART 118784
#define NCHUNK 256
#define PART_FLOATS (NCHUNK * 8 * MM)
#define WS_NEED_PART ((size_t)(OFF_PART + PART_FLOATS) * 4)

typedef float f2 __attribute__((ext_vector_type(2)));

__device__ __forceinline__ f2 vfma(f2 a, f2 b, f2 c) {
    f2 r; r.x = fmaf(a.x, b.x, c.x); r.y = fmaf(a.y, b.y, c.y); return r;
}

__global__ __launch_bounds__(256) void init_k(const float* __restrict__ V,
                                              const float* __restrict__ pts,
                                              const float* __restrict__ w,
                                              float* __restrict__ ws) {
#pragma clang fp contract(off)
    int i = blockIdx.x * 256 + threadIdx.x;
    float x = pts[3 * i], y = pts[3 * i + 1], z = pts[3 * i + 2];
    float cvw = CGREEN * (V[i] * w[i]);
    float xx = x * x, yy = y * y, zz = z * z;
    float r2 = (xx + yy) + zz;                 // np rounding order
    float* cp = ws + i * 12;
    cp[0] = x; cp[1] = y; cp[2] = z; cp[3] = r2;
    ws[OFF_VW + i] = cvw;
#pragma unroll
    for (int n = 0; n < NK; n++) {
        float kk = 0.5f * (float)(n + 1);
        float s, c;
        sincosf(kk * z, &s, &c);
        ws[OFF_P0R + n * MM + i] = c;
        ws[OFF_P0I + n * MM + i] = s;
        cp[4 + n] = cvw * c;
        cp[8 + n] = cvw * s;
        ws[OFF_YR + n * MM + i] = 0.0f;
        ws[OFF_YI + n * MM + i] = 0.0f;
    }
}

// One column vs TWO rows; D^2/trans/recurrence packed across the row pair.
__device__ __forceinline__ void body_col2(f2 rx, f2 ry, f2 rz, f2 rr2,
                                          int r0, int r1, int jg,
                                          float4 A, float4 R, float4 I,
                                          f2 acc0[4], f2 acc1[4]) {
    // ---- bit-faithful D^2, per-element rounding == reference sequence ----
    f2 d2;
    {
#pragma clang fp contract(off)
        f2 m; m.x = rx.x * A.x; m.y = rx.y * A.x;          // rounded mul
        m = vfma(ry, (f2){A.y, A.y}, m);                   // k-order fma chain
        m = vfma(rz, (f2){A.z, A.z}, m);
        f2 r2s = rr2 + A.w;                                // rounded add
        f2 twod = 2.0f * m;                                // exact
        d2 = r2s - twod;                                   // single rounded sub
    }
    d2.x = fmaxf(d2.x, 1e-12f);
    d2.y = fmaxf(d2.y, 1e-12f);
    // ---- fast-math (proven invisible in bucketed output) ----
    float ia = __builtin_amdgcn_rsqf(d2.x);
    float ib = __builtin_amdgcn_rsqf(d2.y);
    f2 invD = {ia, ib};
    f2 rev = d2 * invD * (0.5f * INV2PI);   // angle 0.5*D in revolutions
    float sca = (jg == r0) ? 0.0f : ia;
    float scb = (jg == r1) ? 0.0f : ib;
    f2 s1, c1;
    s1.x = __builtin_amdgcn_sinf(rev.x);    // raw v_sin: sin(2*pi*x)
    c1.x = __builtin_amdgcn_cosf(rev.x);
    s1.y = __builtin_amdgcn_sinf(rev.y);
    c1.y = __builtin_amdgcn_cosf(rev.y);
    f2 c2 = vfma(c1, c1, -(s1 * s1));
    f2 s2 = 2.0f * (c1 * s1);
    f2 c3 = vfma(c2, c1, -(s2 * s1));
    f2 s3 = vfma(s2, c1, c2 * s1);
    f2 c4 = vfma(c2, c2, -(s2 * s2));
    f2 s4 = 2.0f * (c2 * s2);
#define ACC_UPD(nn, CC, SS, ZR, ZI)                                          \
    {                                                                        \
        f2 ri = {ZR, ZI}, sw = {-ZI, ZR};                                    \
        f2 t0 = CC.x * ri; t0 = vfma((f2){SS.x, SS.x}, sw, t0);              \
        acc0[nn] = vfma((f2){sca, sca}, t0, acc0[nn]);                       \
        f2 t1 = CC.y * ri; t1 = vfma((f2){SS.y, SS.y}, sw, t1);              \
        acc1[nn] = vfma((f2){scb, scb}, t1, acc1[nn]);                       \
    }
    ACC_UPD(0, c1, s1, R.x, I.x)
    ACC_UPD(1, c2, s2, R.y, I.y)
    ACC_UPD(2, c3, s3, R.z, I.z)
    ACC_UPD(3, c4, s4, R.w, I.w)
#undef ACC_UPD
}

// grid: (C chunks, 8 row-groups of 512); block 256; 2 rows/thread.
template <int C, bool USE_PART>
__global__ __launch_bounds__(256) void matvec_k(const float* __restrict__ cols,
                                                f2* __restrict__ part,
                                                float* __restrict__ yr,
                                                float* __restrict__ yi) {
    constexpr int TC = MM / C;                 // cols per block (16)
    const int chunk = blockIdx.x;
    const int rg = blockIdx.y;
    const int r0 = rg * 512 + threadIdx.x;
    const int r1 = r0 + 256;
    const float4 rowA = *(const float4*)&cols[r0 * 12];   // x,y,z,r2
    const float4 rowB = *(const float4*)&cols[r1 * 12];
    const f2 rx = {rowA.x, rowB.x}, ry = {rowA.y, rowB.y};
    const f2 rz = {rowA.z, rowB.z}, rr2 = {rowA.w, rowB.w};
    f2 acc0[4], acc1[4];
#pragma unroll
    for (int i = 0; i < 4; i++) {
        acc0[i].x = 0.0f; acc0[i].y = 0.0f;
        acc1[i].x = 0.0f; acc1[i].y = 0.0f;
    }
    const int jg0 = chunk * TC;
    const float* colbase = cols + (size_t)jg0 * 12;   // uniform across lanes
#pragma unroll 4
    for (int j = 0; j < TC; j++) {
        const float4* cp = (const float4*)(colbase + j * 12);
        float4 A = cp[0], R = cp[1], I = cp[2];
        body_col2(rx, ry, rz, rr2, r0, r1, jg0 + j, A, R, I, acc0, acc1);
    }
    if (USE_PART) {
#pragma unroll
        for (int n = 0; n < NK; n++) {
            part[(size_t)(chunk * 4 + n) * MM + r0] = acc0[n];
            part[(size_t)(chunk * 4 + n) * MM + r1] = acc1[n];
        }
    } else {
#pragma unroll
        for (int n = 0; n < NK; n++) {
            atomicAdd(&yr[n * MM + r0], acc0[n].x);
            atomicAdd(&yi[n * MM + r0], acc0[n].y);
            atomicAdd(&yr[n * MM + r1], acc1[n].x);
            atomicAdd(&yi[n * MM + r1], acc1[n].y);
        }
    }
}

// Fused chunk-reduction + psi update. 256 blocks x 64: thread per (n,row);
// 8 independent f2 accumulators for MLP.
template <int C>
__global__ __launch_bounds__(64) void reduce_update_k(float* __restrict__ ws) {
    int tid = blockIdx.x * 64 + threadIdx.x;       // [0, 16384)
    int row = tid & (MM - 1);
    int n = tid >> 12;                              // 0..3
    const f2* part2 = (const f2*)(ws + OFF_PART);
    f2 s[8];
#pragma unroll
    for (int u = 0; u < 8; u++) { s[u].x = 0.0f; s[u].y = 0.0f; }
    for (int c = 0; c < C; c += 8) {
#pragma unroll
        for (int u = 0; u < 8; u++)
            s[u] += part2[(size_t)((c + u) * 4 + n) * MM + row];
    }
    f2 t = ((s[0] + s[1]) + (s[2] + s[3])) + ((s[4] + s[5]) + (s[6] + s[7]));
    float cvw = ws[OFF_VW + row];
    float pr = ws[OFF_P0R + n * MM + row] + t.x;
    float pi = ws[OFF_P0I + n * MM + row] + t.y;
    ws[row * 12 + 4 + n] = cvw * pr;
    ws[row * 12 + 8 + n] = cvw * pi;
}

// atomic-fallback update (only used if ws too small for partials)
__global__ __launch_bounds__(256) void update_fallback_k(float* __restrict__ ws) {
    int i = blockIdx.x * 256 + threadIdx.x;
    float cvw = ws[OFF_VW + i];
#pragma unroll
    for (int n = 0; n < NK; n++) {
        float pr = ws[OFF_P0R + n * MM + i] + ws[OFF_YR + n * MM + i];
        float pi = ws[OFF_P0I + n * MM + i] + ws[OFF_YI + n * MM + i];
        ws[i * 12 + 4 + n] = cvw * pr;
        ws[i * 12 + 8 + n] = cvw * pi;
        ws[OFF_YR + n * MM + i] = 0.0f;
        ws[OFF_YI + n * MM + i] = 0.0f;
    }
}

// 512 blocks: (k, obs_dir, j-half). float4 loads from the colpack.
__global__ __launch_bounds__(256) void far_k(const float* __restrict__ obs,
                                             const float* __restrict__ ws,
                                             float* __restrict__ out) {
    int kidx = (blockIdx.x >> 1) >> 6;
    int d = (blockIdx.x >> 1) & 63;
    int half = blockIdx.x & 1;
    float kk = 0.5f * (float)(kidx + 1);
    float ox = obs[3 * d], oy = obs[3 * d + 1], oz = obs[3 * d + 2];
    float fr = 0.0f, fi = 0.0f;
    for (int j = half * 2048 + threadIdx.x; j < half * 2048 + 2048; j += 256) {
        const float4* c4 = (const float4*)(ws + j * 12);
        float4 P = c4[0], AR = c4[1], AI = c4[2];
        float q = fmaf(P.z, oz, fmaf(P.y, oy, P.x * ox));
        float ar, ai;
        switch (kidx) {
            case 0: ar = AR.x; ai = AI.x; break;
            case 1: ar = AR.y; ai = AI.y; break;
            case 2: ar = AR.z; ai = AI.z; break;
            default: ar = AR.w; ai = AI.w; break;
        }
        float s, co;
        __sincosf(kk * q, &s, &co);
        fr += fmaf(ar, co,  ai * s);
        fi += fmaf(ai, co, -ar * s);
    }
#pragma unroll
    for (int off = 32; off > 0; off >>= 1) {
        fr += __shfl_down(fr, off);
        fi += __shfl_down(fi, off);
    }
    __shared__ float red[4][2];
    int wave = threadIdx.x >> 6;
    if ((threadIdx.x & 63) == 0) { red[wave][0] = fr; red[wave][1] = fi; }
    __syncthreads();
    if (threadIdx.x == 0) {
        fr = red[0][0] + red[1][0] + red[2][0] + red[3][0];
        fi = red[0][1] + red[1][1] + red[2][1] + red[3][1];
        atomicAdd(&out[(kidx * 64 + d) * 2 + 0], -fr);
        atomicAdd(&out[(kidx * 64 + d) * 2 + 1], -fi);
    }
}

extern "C" void kernel_launch(void* const* d_in, const int* in_sizes, int n_in,
                              void* d_out, int out_size, void* d_ws, size_t ws_size,
                              hipStream_t stream) {
    const float* V   = (const float*)d_in[0];
    const float* obs = (const float*)d_in[1];
    const float* pts = (const float*)d_in[2];
    const float* w   = (const float*)d_in[3];
    float* ws  = (float*)d_ws;
    float* out = (float*)d_out;

    // d_out is re-poisoned before every call: zero it (far_k accumulates)
    hipMemsetAsync(out, 0, (size_t)out_size * 4, stream);

    init_k<<<16, 256, 0, stream>>>(V, pts, w, ws);
    if (ws_size >= WS_NEED_PART) {
        for (int it = 0; it < 5; it++) {
            matvec_k<NCHUNK, true><<<dim3(NCHUNK, 8), 256, 0, stream>>>(
                ws, (f2*)(ws + OFF_PART), ws + OFF_YR, ws + OFF_YI);
            reduce_update_k<NCHUNK><<<256, 64, 0, stream>>>(ws);
        }
    } else {
        for (int it = 0; it < 5; it++) {
            matvec_k<64, false><<<dim3(64, 8), 256, 0, stream>>>(
                ws, (f2*)(ws + OFF_PART), ws + OFF_YR, ws + OFF_YI);
            update_fallback_k<<<16, 256, 0, stream>>>(ws);
        }
    }
    far_k<<<512, 256, 0, stream>>>(obs, ws, out);
}

// Round 16
// 219.435 us; speedup vs baseline: 1.1674x; 1.1674x over previous
//
#include <hip/hip_runtime.h>

// Born-series scattering, fully fused recompute-G approach.
// M=4096 pts, 4 wavenumbers (0.5,1,1.5,2), 5 Born iterations, 64 obs dirs.
// R4: bit-faithful D^2 (Gram rounding sequence) -> absmax 0.0.
// R5-R8: atomics eliminated; fused chunk-reduce (~3.5us).
// R9-R15: eight probes on the ~25us matvec plateau (packed math, s_load
//   promotion, row-pair ILP, LDS pipeline, manual phasing, 2x residency,
//   2x chunks) all neutral or regressed. The body's serial
//   load->D2->rsq->sincos->recurrence chain is trans-pipe-bound; extra
//   waves collide on the shared quarter-rate trans pipe (R15 proof).
// R16: revert to best-measured config (R14, 220.07us) verbatim.
//
// ws layout (floats):
//   colpack[M][12]: x,y,z,r2, ar[4], ai[4]          (a = C * vw * psi, per k)
//   cvw[M]; p0r[4][M], p0i[4][M]; yr[4][M], yi[4][M] (fallback)
//   part[C][4][M] of float2                          (partials, 16MB)

#define MM 4096
#define NK 4
#define CGREEN 0.07957747154594767f   // 1/(4*pi)
#define INV2PI 0.15915494309189535f   // 1/(2*pi)

#define OFF_VW   49152
#define OFF_P0R  53248
#define OFF_P0I  69632
#define OFF_YR   86016
#define OFF_YI   102400
#define OFF_PART 118784
#define NCHUNK 128
#define PART_FLOATS (NCHUNK * 8 * MM)
#define WS_NEED_PART ((size_t)(OFF_PART + PART_FLOATS) * 4)

typedef float f2 __attribute__((ext_vector_type(2)));

__device__ __forceinline__ f2 vfma(f2 a, f2 b, f2 c) {
    f2 r; r.x = fmaf(a.x, b.x, c.x); r.y = fmaf(a.y, b.y, c.y); return r;
}

__global__ __launch_bounds__(256) void init_k(const float* __restrict__ V,
                                              const float* __restrict__ pts,
                                              const float* __restrict__ w,
                                              float* __restrict__ ws) {
#pragma clang fp contract(off)
    int i = blockIdx.x * 256 + threadIdx.x;
    float x = pts[3 * i], y = pts[3 * i + 1], z = pts[3 * i + 2];
    float cvw = CGREEN * (V[i] * w[i]);
    float xx = x * x, yy = y * y, zz = z * z;
    float r2 = (xx + yy) + zz;                 // np rounding order
    float* cp = ws + i * 12;
    cp[0] = x; cp[1] = y; cp[2] = z; cp[3] = r2;
    ws[OFF_VW + i] = cvw;
#pragma unroll
    for (int n = 0; n < NK; n++) {
        float kk = 0.5f * (float)(n + 1);
        float s, c;
        sincosf(kk * z, &s, &c);
        ws[OFF_P0R + n * MM + i] = c;
        ws[OFF_P0I + n * MM + i] = s;
        cp[4 + n] = cvw * c;
        cp[8 + n] = cvw * s;
        ws[OFF_YR + n * MM + i] = 0.0f;
        ws[OFF_YI + n * MM + i] = 0.0f;
    }
}

// One column vs TWO rows; D^2/trans/recurrence packed across the row pair.
__device__ __forceinline__ void body_col2(f2 rx, f2 ry, f2 rz, f2 rr2,
                                          int r0, int r1, int jg,
                                          float4 A, float4 R, float4 I,
                                          f2 acc0[4], f2 acc1[4]) {
    // ---- bit-faithful D^2, per-element rounding == reference sequence ----
    f2 d2;
    {
#pragma clang fp contract(off)
        f2 m; m.x = rx.x * A.x; m.y = rx.y * A.x;          // rounded mul
        m = vfma(ry, (f2){A.y, A.y}, m);                   // k-order fma chain
        m = vfma(rz, (f2){A.z, A.z}, m);
        f2 r2s = rr2 + A.w;                                // rounded add
        f2 twod = 2.0f * m;                                // exact
        d2 = r2s - twod;                                   // single rounded sub
    }
    d2.x = fmaxf(d2.x, 1e-12f);
    d2.y = fmaxf(d2.y, 1e-12f);
    // ---- fast-math (proven invisible in bucketed output) ----
    float ia = __builtin_amdgcn_rsqf(d2.x);
    float ib = __builtin_amdgcn_rsqf(d2.y);
    f2 invD = {ia, ib};
    f2 rev = d2 * invD * (0.5f * INV2PI);   // angle 0.5*D in revolutions
    float sca = (jg == r0) ? 0.0f : ia;
    float scb = (jg == r1) ? 0.0f : ib;
    f2 s1, c1;
    s1.x = __builtin_amdgcn_sinf(rev.x);    // raw v_sin: sin(2*pi*x)
    c1.x = __builtin_amdgcn_cosf(rev.x);
    s1.y = __builtin_amdgcn_sinf(rev.y);
    c1.y = __builtin_amdgcn_cosf(rev.y);
    f2 c2 = vfma(c1, c1, -(s1 * s1));
    f2 s2 = 2.0f * (c1 * s1);
    f2 c3 = vfma(c2, c1, -(s2 * s1));
    f2 s3 = vfma(s2, c1, c2 * s1);
    f2 c4 = vfma(c2, c2, -(s2 * s2));
    f2 s4 = 2.0f * (c2 * s2);
#define ACC_UPD(nn, CC, SS, ZR, ZI)                                          \
    {                                                                        \
        f2 ri = {ZR, ZI}, sw = {-ZI, ZR};                                    \
        f2 t0 = CC.x * ri; t0 = vfma((f2){SS.x, SS.x}, sw, t0);              \
        acc0[nn] = vfma((f2){sca, sca}, t0, acc0[nn]);                       \
        f2 t1 = CC.y * ri; t1 = vfma((f2){SS.y, SS.y}, sw, t1);              \
        acc1[nn] = vfma((f2){scb, scb}, t1, acc1[nn]);                       \
    }
    ACC_UPD(0, c1, s1, R.x, I.x)
    ACC_UPD(1, c2, s2, R.y, I.y)
    ACC_UPD(2, c3, s3, R.z, I.z)
    ACC_UPD(3, c4, s4, R.w, I.w)
#undef ACC_UPD
}

// grid: (C chunks, 8 row-groups of 512); block 256; 2 rows/thread.
template <int C, bool USE_PART>
__global__ __launch_bounds__(256) void matvec_k(const float* __restrict__ cols,
                                                f2* __restrict__ part,
                                                float* __restrict__ yr,
                                                float* __restrict__ yi) {
    constexpr int TC = MM / C;                 // cols per block (32)
    const int chunk = blockIdx.x;
    const int rg = blockIdx.y;
    const int r0 = rg * 512 + threadIdx.x;
    const int r1 = r0 + 256;
    const float4 rowA = *(const float4*)&cols[r0 * 12];   // x,y,z,r2
    const float4 rowB = *(const float4*)&cols[r1 * 12];
    const f2 rx = {rowA.x, rowB.x}, ry = {rowA.y, rowB.y};
    const f2 rz = {rowA.z, rowB.z}, rr2 = {rowA.w, rowB.w};
    f2 acc0[4], acc1[4];
#pragma unroll
    for (int i = 0; i < 4; i++) {
        acc0[i].x = 0.0f; acc0[i].y = 0.0f;
        acc1[i].x = 0.0f; acc1[i].y = 0.0f;
    }
    const int jg0 = chunk * TC;
    const float* colbase = cols + (size_t)jg0 * 12;   // uniform across lanes
#pragma unroll 4
    for (int j = 0; j < TC; j++) {
        const float4* cp = (const float4*)(colbase + j * 12);
        float4 A = cp[0], R = cp[1], I = cp[2];
        body_col2(rx, ry, rz, rr2, r0, r1, jg0 + j, A, R, I, acc0, acc1);
    }
    if (USE_PART) {
#pragma unroll
        for (int n = 0; n < NK; n++) {
            part[(size_t)(chunk * 4 + n) * MM + r0] = acc0[n];
            part[(size_t)(chunk * 4 + n) * MM + r1] = acc1[n];
        }
    } else {
#pragma unroll
        for (int n = 0; n < NK; n++) {
            atomicAdd(&yr[n * MM + r0], acc0[n].x);
            atomicAdd(&yi[n * MM + r0], acc0[n].y);
            atomicAdd(&yr[n * MM + r1], acc1[n].x);
            atomicAdd(&yi[n * MM + r1], acc1[n].y);
        }
    }
}

// Fused chunk-reduction + psi update. 256 blocks x 64: thread per (n,row);
// 8 independent f2 accumulators for MLP.
template <int C>
__global__ __launch_bounds__(64) void reduce_update_k(float* __restrict__ ws) {
    int tid = blockIdx.x * 64 + threadIdx.x;       // [0, 16384)
    int row = tid & (MM - 1);
    int n = tid >> 12;                              // 0..3
    const f2* part2 = (const f2*)(ws + OFF_PART);
    f2 s[8];
#pragma unroll
    for (int u = 0; u < 8; u++) { s[u].x = 0.0f; s[u].y = 0.0f; }
    for (int c = 0; c < C; c += 8) {
#pragma unroll
        for (int u = 0; u < 8; u++)
            s[u] += part2[(size_t)((c + u) * 4 + n) * MM + row];
    }
    f2 t = ((s[0] + s[1]) + (s[2] + s[3])) + ((s[4] + s[5]) + (s[6] + s[7]));
    float cvw = ws[OFF_VW + row];
    float pr = ws[OFF_P0R + n * MM + row] + t.x;
    float pi = ws[OFF_P0I + n * MM + row] + t.y;
    ws[row * 12 + 4 + n] = cvw * pr;
    ws[row * 12 + 8 + n] = cvw * pi;
}

// atomic-fallback update (only used if ws too small for partials)
__global__ __launch_bounds__(256) void update_fallback_k(float* __restrict__ ws) {
    int i = blockIdx.x * 256 + threadIdx.x;
    float cvw = ws[OFF_VW + i];
#pragma unroll
    for (int n = 0; n < NK; n++) {
        float pr = ws[OFF_P0R + n * MM + i] + ws[OFF_YR + n * MM + i];
        float pi = ws[OFF_P0I + n * MM + i] + ws[OFF_YI + n * MM + i];
        ws[i * 12 + 4 + n] = cvw * pr;
        ws[i * 12 + 8 + n] = cvw * pi;
        ws[OFF_YR + n * MM + i] = 0.0f;
        ws[OFF_YI + n * MM + i] = 0.0f;
    }
}

// 512 blocks: (k, obs_dir, j-half). float4 loads from the colpack.
__global__ __launch_bounds__(256) void far_k(const float* __restrict__ obs,
                                             const float* __restrict__ ws,
                                             float* __restrict__ out) {
    int kidx = (blockIdx.x >> 1) >> 6;
    int d = (blockIdx.x >> 1) & 63;
    int half = blockIdx.x & 1;
    float kk = 0.5f * (float)(kidx + 1);
    float ox = obs[3 * d], oy = obs[3 * d + 1], oz = obs[3 * d + 2];
    float fr = 0.0f, fi = 0.0f;
    for (int j = half * 2048 + threadIdx.x; j < half * 2048 + 2048; j += 256) {
        const float4* c4 = (const float4*)(ws + j * 12);
        float4 P = c4[0], AR = c4[1], AI = c4[2];
        float q = fmaf(P.z, oz, fmaf(P.y, oy, P.x * ox));
        float ar, ai;
        switch (kidx) {
            case 0: ar = AR.x; ai = AI.x; break;
            case 1: ar = AR.y; ai = AI.y; break;
            case 2: ar = AR.z; ai = AI.z; break;
            default: ar = AR.w; ai = AI.w; break;
        }
        float s, co;
        __sincosf(kk * q, &s, &co);
        fr += fmaf(ar, co,  ai * s);
        fi += fmaf(ai, co, -ar * s);
    }
#pragma unroll
    for (int off = 32; off > 0; off >>= 1) {
        fr += __shfl_down(fr, off);
        fi += __shfl_down(fi, off);
    }
    __shared__ float red[4][2];
    int wave = threadIdx.x >> 6;
    if ((threadIdx.x & 63) == 0) { red[wave][0] = fr; red[wave][1] = fi; }
    __syncthreads();
    if (threadIdx.x == 0) {
        fr = red[0][0] + red[1][0] + red[2][0] + red[3][0];
        fi = red[0][1] + red[1][1] + red[2][1] + red[3][1];
        atomicAdd(&out[(kidx * 64 + d) * 2 + 0], -fr);
        atomicAdd(&out[(kidx * 64 + d) * 2 + 1], -fi);
    }
}

extern "C" void kernel_launch(void* const* d_in, const int* in_sizes, int n_in,
                              void* d_out, int out_size, void* d_ws, size_t ws_size,
                              hipStream_t stream) {
    const float* V   = (const float*)d_in[0];
    const float* obs = (const float*)d_in[1];
    const float* pts = (const float*)d_in[2];
    const float* w   = (const float*)d_in[3];
    float* ws  = (float*)d_ws;
    float* out = (float*)d_out;

    // d_out is re-poisoned before every call: zero it (far_k accumulates)
    hipMemsetAsync(out, 0, (size_t)out_size * 4, stream);

    init_k<<<16, 256, 0, stream>>>(V, pts, w, ws);
    if (ws_size >= WS_NEED_PART) {
        for (int it = 0; it < 5; it++) {
            matvec_k<NCHUNK, true><<<dim3(NCHUNK, 8), 256, 0, stream>>>(
                ws, (f2*)(ws + OFF_PART), ws + OFF_YR, ws + OFF_YI);
            reduce_update_k<NCHUNK><<<256, 64, 0, stream>>>(ws);
        }
    } else {
        for (int it = 0; it < 5; it++) {
            matvec_k<64, false><<<dim3(64, 8), 256, 0, stream>>>(
                ws, (f2*)(ws + OFF_PART), ws + OFF_YR, ws + OFF_YI);
            update_fallback_k<<<16, 256, 0, stream>>>(ws);
        }
    }
    far_k<<<512, 256, 0, stream>>>(obs, ws, out);
}